// Round 11
// baseline (244.796 us; speedup 1.0000x reference)
//
#include <hip/hip_runtime.h>

typedef unsigned short u16;
typedef unsigned int u32;
typedef __bf16 bf16x8 __attribute__((ext_vector_type(8)));
typedef float f32x4 __attribute__((ext_vector_type(4)));
typedef float f32x16 __attribute__((ext_vector_type(16)));
typedef u16 u16x8 __attribute__((ext_vector_type(8)));
typedef u16 u16x4 __attribute__((ext_vector_type(4)));
typedef u32 u32x2 __attribute__((ext_vector_type(2)));
typedef u32 u32x4 __attribute__((ext_vector_type(4)));

#define LN_EPS 1e-5f
#define SIG_SCALE_F 0.35355339059327379f /* 64^-0.25 */
#define NLOG2E -1.4426950408889634f
#define BIAS_L2E 4.328085122666891f /* 3*log2(e) */

__device__ __forceinline__ u16 f2bf(float f) {
    u32 u = __builtin_bit_cast(u32, f);
    u32 r = u + 0x7fffu + ((u >> 16) & 1u);
    return (u16)(r >> 16);
}
__device__ __forceinline__ float bf2f(u16 v) {
    return __builtin_bit_cast(float, (u32)v << 16);
}
// pack high-16s of two f32 (truncating bf16 cvt, 1 v_perm): low16=a, high16=b
__device__ __forceinline__ u32 pk_hi(float a, float b) {
    return __builtin_amdgcn_perm(__builtin_bit_cast(u32, b), __builtin_bit_cast(u32, a),
                                 0x07060302u);
}

// async global->LDS, 16B per lane; lds base wave-uniform (HW adds lane*16)
__device__ __forceinline__ void gload16(const u16* g, u16* lds) {
    __builtin_amdgcn_global_load_lds(
        (const __attribute__((address_space(1))) u32*)g,
        (__attribute__((address_space(3))) u32*)lds, 16, 0, 0);
}

// 128B-row XOR-swizzled fragment read: LDS chunk ch holds global chunk
// ch^(row&7); reading global chunk kidx -> LDS chunk kidx^(row&7).
__device__ __forceinline__ bf16x8 frag64(const u16* base, int row, int kidx) {
    return *(const bf16x8*)(base + row * 64 + ((kidx ^ (row & 7)) * 8));
}

// ---------------------------------------------------------------------------
// GEMM core: acc[4][4] += A[M,K] @ B[N,K]^T 128x128 tile, BK=64 (v15: half
// the barrier drains of BK=32; measured -3us vs BK=32). 32 MFMA per barrier
// pair. LDS 2x16KB, 128B rows with (row&7) XOR chunk swizzle. Default block
// mapping (v16's XCD remap regressed +6us -- wrong regime for L2-resident
// N=1024; default dispatch order has better temporal A-panel reuse).
// ---------------------------------------------------------------------------
__device__ __forceinline__ void gemm_core(f32x4 acc[4][4],
                                          const u16* __restrict__ A, const u16* __restrict__ B,
                                          int Kiter, int lda, int ldb,
                                          long m0, long n0, u16* As, u16* Bs) {
    const int tid = threadIdx.x;
    const int lane = tid & 63;
    const int wave = tid >> 6;
    const int r15 = lane & 15;
    const int qd = lane >> 4;
    const int wm = (wave >> 1) * 64;
    const int wn = (wave & 1) * 64;

    // staging: 16 segs of 8 rows (128B each); wave w stages segs 4w..4w+3
    const int lr0 = lane >> 3;
    const int lc0 = lane & 7;
    const u16* Aps[4];
    const u16* Bps[4];
#pragma unroll
    for (int i = 0; i < 4; i++) {
        int s = wave * 4 + i;
        int row = s * 8 + lr0;
        int c = lc0 ^ (row & 7);
        Aps[i] = A + (m0 + row) * lda + c * 8;
        Bps[i] = B + (n0 + row) * ldb + c * 8;
    }

    for (int kt = 0; kt < Kiter; kt += 64) {
        __syncthreads();
#pragma unroll
        for (int i = 0; i < 4; i++) {
            gload16(Aps[i] + kt, As + (wave * 4 + i) * 512);
            gload16(Bps[i] + kt, Bs + (wave * 4 + i) * 512);
        }
        __syncthreads();
#pragma unroll
        for (int kk = 0; kk < 2; kk++) {
            bf16x8 af[4], bfr[4];
#pragma unroll
            for (int i = 0; i < 4; i++)
                af[i] = frag64(As, wm + i * 16 + r15, kk * 4 + qd);
#pragma unroll
            for (int j = 0; j < 4; j++)
                bfr[j] = frag64(Bs, wn + j * 16 + r15, kk * 4 + qd);
#pragma unroll
            for (int i = 0; i < 4; i++)
#pragma unroll
                for (int j = 0; j < 4; j++)
                    acc[i][j] = __builtin_amdgcn_mfma_f32_16x16x32_bf16(af[i], bfr[j], acc[i][j], 0, 0, 0);
        }
    }
}

// ---------------------------------------------------------------------------
// Fused q/k/v projections, v18: launch_bounds (256,3) -> (256,4). The core
// hides the per-K-step barrier drain via block-level TLP (m114 mechanism);
// gemm_o already runs the identical core at 4 blocks/CU spill-free. LDS
// 32KB/block -> 4 fit. One more resident block/CU = +33% latency hiding.
// z<=1: per-head LN epilogue (z==0 folds -log2(e)*SIG_SCALE into the
// affine). z==2: V written transposed into vt[(b*16+h)*64+d][2048].
// ---------------------------------------------------------------------------
__global__ __launch_bounds__(256, 4) void gemm_qkv(const u16* __restrict__ xq, const u16* __restrict__ keyb,
                                                   const u16* __restrict__ Wqb, const u16* __restrict__ Wkb,
                                                   const u16* __restrict__ Wvb,
                                                   const float* __restrict__ qns, const float* __restrict__ qnb,
                                                   const float* __restrict__ kns, const float* __restrict__ knb,
                                                   u16* __restrict__ qln, u16* __restrict__ kln,
                                                   u16* __restrict__ vt) {
    __shared__ __attribute__((aligned(16))) u16 As[128 * 64];
    __shared__ __attribute__((aligned(16))) u16 Bs[128 * 64];
    const int z = blockIdx.z;
    const u16* A = (z == 0) ? xq : keyb;
    const u16* B = (z == 0) ? Wqb : ((z == 1) ? Wkb : Wvb);
    const long m0 = (long)blockIdx.x * 128;
    const long n0 = (long)blockIdx.y * 128;

    f32x4 acc[4][4];
#pragma unroll
    for (int i = 0; i < 4; i++)
#pragma unroll
        for (int j = 0; j < 4; j++) acc[i][j] = (f32x4){0.f, 0.f, 0.f, 0.f};

    gemm_core(acc, A, B, 1024, 1024, 1024, m0, n0, As, Bs);

    const int lane = threadIdx.x & 63;
    const int wave = threadIdx.x >> 6;
    const int r15 = lane & 15;
    const int qd = lane >> 4;
    const int wm = (wave >> 1) * 64;
    const int wn = (wave & 1) * 64;

    if (z <= 1) {
        u16* C = (z == 0) ? qln : kln;
        const float* sc_ = (z == 0) ? qns : kns;
        const float* bs_ = (z == 0) ? qnb : knb;
        const float post = (z == 0) ? SIG_SCALE_F * NLOG2E : SIG_SCALE_F;
        float scl[4], bia[4];
#pragma unroll
        for (int j = 0; j < 4; j++) {
            scl[j] = sc_[j * 16 + r15] * post;
            bia[j] = bs_[j * 16 + r15] * post;
        }
#pragma unroll
        for (int i = 0; i < 4; i++) {
#pragma unroll
            for (int rr = 0; rr < 4; rr++) {
                float a0 = acc[i][0][rr], a1 = acc[i][1][rr], a2 = acc[i][2][rr], a3 = acc[i][3][rr];
                float s1 = (a0 + a1) + (a2 + a3);
                float s2 = __builtin_fmaf(a3, a3,
                           __builtin_fmaf(a2, a2, __builtin_fmaf(a1, a1, a0 * a0)));
#pragma unroll
                for (int off = 1; off <= 8; off <<= 1) {
                    s1 += __shfl_xor(s1, off, 64);
                    s2 += __shfl_xor(s2, off, 64);
                }
                float mu = s1 * (1.0f / 64.0f);
                float var = __builtin_fmaf(-mu, mu, s2 * (1.0f / 64.0f));
                float rs = rsqrtf(var + LN_EPS);
                long row = m0 + wm + i * 16 + qd * 4 + rr;
#pragma unroll
                for (int j = 0; j < 4; j++) {
                    long col = n0 + wn + j * 16 + r15;
                    float o = __builtin_fmaf((acc[i][j][rr] - mu) * rs, scl[j], bia[j]);
                    C[row * 1024 + col] = f2bf(o);
                }
            }
        }
    } else {
        // direct transposed V write: row -> (b, kk), col -> (h, d)
#pragma unroll
        for (int i = 0; i < 4; i++)
#pragma unroll
            for (int rr = 0; rr < 4; rr++) {
                int grow = (int)(m0 + wm + i * 16 + qd * 4 + rr);
                int bb = grow >> 11;
                int kk = grow & 2047;
#pragma unroll
                for (int j = 0; j < 4; j++) {
                    int col = (int)(n0 + wn + j * 16 + r15);
                    int hh = col >> 6;
                    int dd = col & 63;
                    vt[((size_t)(bb * 16 + hh) * 64 + dd) * 2048 + kk] = f2bf(acc[i][j][rr]);
                }
            }
    }
}

// output projection, split-K=2: grid (32, 8, 2), K=512/block (8 BK-64 iters),
// bf16 partials. Half the partial traffic of split-K=4 (measured ~-9us total).
__global__ __launch_bounds__(256, 4) void gemm_o(const u16* __restrict__ ctx, const u16* __restrict__ Wob,
                                                 u16* __restrict__ opre) {
    __shared__ __attribute__((aligned(16))) u16 As[128 * 64];
    __shared__ __attribute__((aligned(16))) u16 Bs[128 * 64];
    const int z = blockIdx.z;
    const int koff = z * 512;
    u16* C = opre + (size_t)z * 4194304;
    const long m0 = (long)blockIdx.x * 128;
    const long n0 = (long)blockIdx.y * 128;
    f32x4 acc[4][4];
#pragma unroll
    for (int i = 0; i < 4; i++)
#pragma unroll
        for (int j = 0; j < 4; j++) acc[i][j] = (f32x4){0.f, 0.f, 0.f, 0.f};
    gemm_core(acc, ctx + koff, Wob + koff, 512, 1024, 1024, m0, n0, As, Bs);

    const int lane = threadIdx.x & 63;
    const int wave = threadIdx.x >> 6;
    const int r15 = lane & 15;
    const int qd = lane >> 4;
    const int wm = (wave >> 1) * 64;
    const int wn = (wave & 1) * 64;
#pragma unroll
    for (int i = 0; i < 4; i++)
#pragma unroll
        for (int rr = 0; rr < 4; rr++) {
            long row = m0 + wm + i * 16 + qd * 4 + rr;
#pragma unroll
            for (int j = 0; j < 4; j++)
                C[row * 1024 + n0 + wn + j * 16 + r15] = f2bf(acc[i][j][rr]);
        }
}

// ---------------------------------------------------------------------------
// Fused sigmoid attention v14 (UNCHANGED -- best measured: 51.5us). Pipelined
// stage(i+1) || S(i) || PV(i-1) || sig(i), single pg buffer carrying P
// across one barrier, per-mt-tile S (no spill at the 128-reg cap), 3-slot V
// rotation via SGPR scalars, V slot 2 overlays Qs, LDS 80KB = 2 blocks/CU,
// v_rcp (trans ~2cy issue), accS C-init = BIAS_L2E with q pre-scaled by
// NLOG2E. Register-capped at 4 waves/SIMD; residual ~46% latency stall is
// structural at this occupancy.
// ---------------------------------------------------------------------------
__global__ __launch_bounds__(512, 4) void attn_sigmoid_v14(const u16* __restrict__ q,
                                                           const u16* __restrict__ k,
                                                           const u16* __restrict__ vt,
                                                           u16* __restrict__ ctx) {
    // [Qs | V slot2] 16K, Ks[2][2] 32K, Vs[slot0..1][2] 32K  = 80 KB
    __shared__ __attribute__((aligned(16))) u16 Sh[8192 + 16384 + 16384];
    u16* Qs = Sh;
    u16* Ks = Sh + 8192;
    u16* Vs = Sh + 8192 + 16384;
    float* Obuf = (float*)(Sh + 8192);  // 32 KB, overlays Ks (dead at epilogue)

    const int tid = threadIdx.x;
    const int lane = tid & 63;
    const int wave = tid >> 6;       // 0..7
    const int l31 = lane & 31;
    const int h = lane >> 5;
    const int qsub = wave & 3;       // 32-q-row group
    const int kh = wave >> 2;        // k half
    const int hd = blockIdx.x;       // head (XCD-aligned)
    const int q0 = blockIdx.y * 128;
    const int b = blockIdx.z;
    const int bh = b * 16 + hd;

    const int lr0 = lane >> 3;
    const int lc0 = lane & 7;
    const int wsub = wave & 3;
    const int kbeg = kh * 1024;

    auto kptr = [&](int slot) { return Ks + (slot * 2 + kh) * 4096; };
    auto vptr = [&](int slot) { return (slot == 2 ? Sh : Vs + slot * 8192) + kh * 4096; };

    // stage this kh-half's 64x64 K,V chunk (8+8 segs over the half's 4 waves)
    auto stageKV = [&](int kslot, int vslot, int kc) {
        u16* kd = kptr(kslot);
        u16* vd = vptr(vslot);
#pragma unroll
        for (int i = 0; i < 2; i++) {
            int s = wsub * 2 + i;
            int row = s * 8 + lr0;
            int c = lc0 ^ (row & 7);
            gload16(k + (size_t)(b * 2048 + kc + row) * 1024 + hd * 64 + c * 8, kd + s * 512);
            gload16(vt + (size_t)(bh * 64 + row) * 2048 + kc + c * 8, vd + s * 512);
        }
    };

    {   // stage Q tile 128x64 (16 segs, wave stages segs {2w, 2w+1}) + chunk 0
#pragma unroll
        for (int i = 0; i < 2; i++) {
            int s = wave * 2 + i;
            int row = s * 8 + lr0;
            int c = lc0 ^ (row & 7);
            gload16(q + (size_t)(b * 2048 + q0 + row) * 1024 + hd * 64 + c * 8, Qs + s * 512);
        }
        stageKV(0, 0, kbeg);
    }
    __syncthreads();
    // hoist Q B-frags: wave's 32 q-rows = qsub*32 + l31  (Qs dead after this)
    bf16x8 qB[4];
#pragma unroll
    for (int dblk = 0; dblk < 4; dblk++)
        qB[dblk] = frag64(Qs, qsub * 32 + l31, dblk * 2 + h);

    f32x16 accO[2];
#pragma unroll
    for (int dt = 0; dt < 2; dt++)
#pragma unroll
        for (int r = 0; r < 16; r++) accO[dt][r] = 0.f;

    u32 pg[2][4][2];

    // S^T for one 32k x 32q tile: C-init = BIAS_L2E (bias via MFMA C-input)
    auto do_S_mt = [&](int kslot, int mt) -> f32x16 {
        const u16* Ksh = kptr(kslot);
        f32x16 s;
#pragma unroll
        for (int r = 0; r < 16; r++) s[r] = BIAS_L2E;
        __builtin_amdgcn_s_setprio(1);
#pragma unroll
        for (int dblk = 0; dblk < 4; dblk++) {
            bf16x8 aK = frag64(Ksh, mt * 32 + l31, dblk * 2 + h);
            s = __builtin_amdgcn_mfma_f32_32x32x16_bf16(aK, qB[dblk], s, 0, 0, 0);
        }
        __builtin_amdgcn_s_setprio(0);
        return s;
    };
    // sigmoid + pack one mt-tile: p = rcp(1 + exp2(s))  (s = NLOG2E*S + BIAS)
    auto do_sig_mt = [&](const f32x16& s, int mt) {
#pragma unroll
        for (int g = 0; g < 4; g++) {
            float p[4];
#pragma unroll
            for (int e = 0; e < 4; e++) {
                float u = __builtin_amdgcn_exp2f(s[g * 4 + e]);
                p[e] = __builtin_amdgcn_rcpf(1.0f + u);
            }
            pg[mt][g][0] = pk_hi(p[0], p[1]);
            pg[mt][g][1] = pk_hi(p[2], p[3]);
        }
    };
    // PV for the previous chunk whose packed P lives in pg
    auto do_PV = [&](int vslot) {
        const u16* Vsh = vptr(vslot);
        __builtin_amdgcn_s_setprio(1);
#pragma unroll
        for (int mt = 0; mt < 2; mt++)
#pragma unroll
            for (int kblk = 0; kblk < 2; kblk++) {
                int glo = kblk * 2, ghi = kblk * 2 + 1;
                u32x2 r0 = __builtin_amdgcn_permlane32_swap(pg[mt][glo][0], pg[mt][ghi][0], false, false);
                u32x2 r1 = __builtin_amdgcn_permlane32_swap(pg[mt][glo][1], pg[mt][ghi][1], false, false);
                u32x4 fr;
                fr[0] = r0[0];
                fr[1] = r1[0];
                fr[2] = r0[1];
                fr[3] = r1[1];
                bf16x8 aP = __builtin_bit_cast(bf16x8, fr);
#pragma unroll
                for (int dt = 0; dt < 2; dt++) {
                    bf16x8 bV = frag64(Vsh, dt * 32 + l31, mt * 4 + kblk * 2 + h);
                    accO[dt] = __builtin_amdgcn_mfma_f32_32x32x16_bf16(aP, bV, accO[dt], 0, 0, 0);
                }
            }
        __builtin_amdgcn_s_setprio(0);
    };

    // V-slot rotation (uniform scalars -> SGPR): chunk i lives in slot i%3
    int vs_prev = 2, vs_cur = 0, vs_next = 1;
#pragma unroll 1
    for (int it = 0; it < 16; ++it) {
        if (it < 15) stageKV((it + 1) & 1, vs_next, kbeg + (it + 1) * 64);
        f32x16 s0 = do_S_mt(it & 1, 0);
        if (it > 0) do_PV(vs_prev);  // reads pg of chunk it-1 (covers s0 latency)
        do_sig_mt(s0, 0);
        f32x16 s1 = do_S_mt(it & 1, 1);
        do_sig_mt(s1, 1);
        __syncthreads();
        int t = vs_prev; vs_prev = vs_cur; vs_cur = vs_next; vs_next = t;
    }
    do_PV(vs_prev);  // drain: PV of chunk 15 (slot 15%3 = 0)

    // merge k-halves through LDS; kh=0 waves write final ctx
    if (kh == 1) {
#pragma unroll
        for (int dt = 0; dt < 2; dt++)
#pragma unroll
            for (int r = 0; r < 16; r++) {
                int ql = qsub * 32 + (r & 3) + 8 * (r >> 2) + 4 * h;
                Obuf[ql * 64 + dt * 32 + l31] = accO[dt][r];
            }
    }
    __syncthreads();
    if (kh == 0) {
#pragma unroll
        for (int dt = 0; dt < 2; dt++)
#pragma unroll
            for (int r = 0; r < 16; r++) {
                int ql = qsub * 32 + (r & 3) + 8 * (r >> 2) + 4 * h;
                float s = accO[dt][r] + Obuf[ql * 64 + dt * 32 + l31];
                ctx[(size_t)(b * 2048 + q0 + ql) * 1024 + hd * 64 + dt * 32 + l31] = f2bf(s);
            }
    }
}

// ---------------------------------------------------------------------------
// prep: fp32->bf16 of 4 weights (blocks 0..4095) + key_feats (4096..6143),
// then row-LN of query (blocks 6144..10239). One launch.
// ---------------------------------------------------------------------------
__global__ __launch_bounds__(256) void prep(const float* __restrict__ w0, const float* __restrict__ w1,
                                            const float* __restrict__ w2, const float* __restrict__ w3,
                                            const float* __restrict__ kf, const float* __restrict__ qf,
                                            const float* __restrict__ lnq_s, const float* __restrict__ lnq_b,
                                            u16* __restrict__ wdst, u16* __restrict__ kdst,
                                            u16* __restrict__ xq) {
    const int bx = blockIdx.x;
    const int tid = threadIdx.x;
    if (bx < 6144) {
        size_t e = ((size_t)bx * 256 + tid) * 4;
        const float* src;
        u16* dst;
        if (e < 4194304) {
            src = ((e >> 20) == 0 ? w0 : (e >> 20) == 1 ? w1 : (e >> 20) == 2 ? w2 : w3) + (e & 1048575);
            dst = wdst + e;
        } else {
            size_t off = e - 4194304;
            src = kf + off;
            dst = kdst + off;
        }
        float4 xv = *(const float4*)src;
        u16x4 o;
        o[0] = f2bf(xv.x);
        o[1] = f2bf(xv.y);
        o[2] = f2bf(xv.z);
        o[3] = f2bf(xv.w);
        *(u16x4*)dst = o;
    } else {
        __shared__ float s1buf[4], s2buf[4];
        const int row = bx - 6144;
        const size_t base = (size_t)row * 1024 + tid * 4;
        const float4 xv = *(const float4*)(qf + base);
        float s1 = xv.x + xv.y + xv.z + xv.w;
        float s2 = xv.x * xv.x + xv.y * xv.y + xv.z * xv.z + xv.w * xv.w;
        int lane = tid & 63, wave = tid >> 6;
#pragma unroll
        for (int off = 32; off > 0; off >>= 1) {
            s1 += __shfl_down(s1, off, 64);
            s2 += __shfl_down(s2, off, 64);
        }
        if (lane == 0) { s1buf[wave] = s1; s2buf[wave] = s2; }
        __syncthreads();
        s1 = s1buf[0] + s1buf[1] + s1buf[2] + s1buf[3];
        s2 = s2buf[0] + s2buf[1] + s2buf[2] + s2buf[3];
        float mu = s1 * (1.0f / 1024.0f);
        float var = s2 * (1.0f / 1024.0f) - mu * mu;
        float rs = rsqrtf(var + LN_EPS);
        const float4 scv = *(const float4*)(lnq_s + tid * 4);
        const float4 bsv = *(const float4*)(lnq_b + tid * 4);
        u16x4 o;
        o[0] = f2bf((xv.x - mu) * rs * scv.x + bsv.x);
        o[1] = f2bf((xv.y - mu) * rs * scv.y + bsv.y);
        o[2] = f2bf((xv.z - mu) * rs * scv.z + bsv.z);
        o[3] = f2bf((xv.w - mu) * rs * scv.w + bsv.w);
        *(u16x4*)(xq + base) = o;
    }
}

// ---------------------------------------------------------------------------
// Final: out = LN(resid + gamma*(o0+o1)) (fp32, bf16 partials, split-K=2)
// ---------------------------------------------------------------------------
__global__ __launch_bounds__(256) void final_ln(const float* __restrict__ resid,
                                                const u16* __restrict__ opre,
                                                const float* __restrict__ gamma,
                                                const float* __restrict__ sc,
                                                const float* __restrict__ bs,
                                                float* __restrict__ out) {
    __shared__ float s1buf[4], s2buf[4];
    const int row = blockIdx.x;
    const int tid = threadIdx.x;
    const size_t base = (size_t)row * 1024 + tid * 4;
    float4 rv = *(const float4*)(resid + base);
    u16x4 p0 = *(const u16x4*)(opre + base);
    u16x4 p1 = *(const u16x4*)(opre + 4194304 + base);
    float4 gv = *(const float4*)(gamma + tid * 4);
    float4 xv;
    xv.x = rv.x + gv.x * (bf2f(p0[0]) + bf2f(p1[0]));
    xv.y = rv.y + gv.y * (bf2f(p0[1]) + bf2f(p1[1]));
    xv.z = rv.z + gv.z * (bf2f(p0[2]) + bf2f(p1[2]));
    xv.w = rv.w + gv.w * (bf2f(p0[3]) + bf2f(p1[3]));
    float s1 = xv.x + xv.y + xv.z + xv.w;
    float s2 = xv.x * xv.x + xv.y * xv.y + xv.z * xv.z + xv.w * xv.w;
    int lane = tid & 63, wave = tid >> 6;
#pragma unroll
    for (int off = 32; off > 0; off >>= 1) {
        s1 += __shfl_down(s1, off, 64);
        s2 += __shfl_down(s2, off, 64);
    }
    if (lane == 0) { s1buf[wave] = s1; s2buf[wave] = s2; }
    __syncthreads();
    s1 = s1buf[0] + s1buf[1] + s1buf[2] + s1buf[3];
    s2 = s2buf[0] + s2buf[1] + s2buf[2] + s2buf[3];
    float mu = s1 * (1.0f / 1024.0f);
    float var = s2 * (1.0f / 1024.0f) - mu * mu;
    float rs = rsqrtf(var + LN_EPS);
    const float4 scv = *(const float4*)(sc + tid * 4);
    const float4 bsv = *(const float4*)(bs + tid * 4);
    float4 o;
    o.x = (xv.x - mu) * rs * scv.x + bsv.x;
    o.y = (xv.y - mu) * rs * scv.y + bsv.y;
    o.z = (xv.z - mu) * rs * scv.z + bsv.z;
    o.w = (xv.w - mu) * rs * scv.w + bsv.w;
    *(float4*)(out + base) = o;
}

extern "C" void kernel_launch(void* const* d_in, const int* in_sizes, int n_in,
                              void* d_out, int out_size, void* d_ws, size_t ws_size,
                              hipStream_t stream) {
    const float* qf    = (const float*)d_in[0];
    const float* kf    = (const float*)d_in[1];
    const float* Wq    = (const float*)d_in[2];
    const float* Wk    = (const float*)d_in[3];
    const float* Wv    = (const float*)d_in[4];
    const float* Wo    = (const float*)d_in[5];
    const float* qn_s  = (const float*)d_in[6];
    const float* qn_b  = (const float*)d_in[7];
    const float* kn_s  = (const float*)d_in[8];
    const float* kn_b  = (const float*)d_in[9];
    const float* lnq_s = (const float*)d_in[10];
    const float* lnq_b = (const float*)d_in[11];
    const float* lno_s = (const float*)d_in[12];
    const float* lno_b = (const float*)d_in[13];
    const float* gamma = (const float*)d_in[14];
    float* out = (float*)d_out;

    char* ws = (char*)d_ws;
    const size_t MB = 1024 * 1024;
    u16* Wqb   = (u16*)(ws + 0 * MB);   // 4 weights contiguous, 8 MB
    u16* Wkb   = (u16*)(ws + 2 * MB);
    u16* Wvb   = (u16*)(ws + 4 * MB);
    u16* Wob   = (u16*)(ws + 6 * MB);
    u16* xq    = (u16*)(ws + 8 * MB);    // dead after gemm_qkv
    u16* ctx   = (u16*)(ws + 8 * MB);    // reuse xq (attn writes merged ctx)
    u16* keyb  = (u16*)(ws + 16 * MB);   // dead after gemm_qkv
    u16* qln   = (u16*)(ws + 24 * MB);   // dead after attn
    u16* kln   = (u16*)(ws + 32 * MB);   // dead after attn
    u16* vt    = (u16*)(ws + 48 * MB);   // written by gemm_qkv z=2, dead after attn
    u16* opre  = (u16*)(ws + 24 * MB);   // 2 x 8 MB partials (reuse 24..40)

    prep<<<dim3(10240), 256, 0, stream>>>(Wq, Wk, Wv, Wo, kf, qf, lnq_s, lnq_b, Wqb, keyb, xq);

    gemm_qkv<<<dim3(32, 8, 3), 256, 0, stream>>>(xq, keyb, Wqb, Wkb, Wvb,
                                                 qn_s, qn_b, kn_s, kn_b, qln, kln, vt);

    attn_sigmoid_v14<<<dim3(16, 16, 2), 512, 0, stream>>>(qln, kln, vt, ctx);

    gemm_o<<<dim3(32, 8, 2), 256, 0, stream>>>(ctx, Wob, opre);
    final_ln<<<dim3(4096), 256, 0, stream>>>(qf, opre, gamma, lno_s, lno_b, out);
}

// Round 12
// 214.483 us; speedup vs baseline: 1.1413x; 1.1413x over previous
//
#include <hip/hip_runtime.h>

typedef unsigned short u16;
typedef unsigned int u32;
typedef __bf16 bf16x8 __attribute__((ext_vector_type(8)));
typedef float f32x4 __attribute__((ext_vector_type(4)));
typedef float f32x16 __attribute__((ext_vector_type(16)));
typedef u16 u16x8 __attribute__((ext_vector_type(8)));
typedef u16 u16x4 __attribute__((ext_vector_type(4)));
typedef u32 u32x2 __attribute__((ext_vector_type(2)));
typedef u32 u32x4 __attribute__((ext_vector_type(4)));

#define LN_EPS 1e-5f
#define SIG_SCALE_F 0.35355339059327379f /* 64^-0.25 */
#define NLOG2E -1.4426950408889634f
#define BIAS_L2E 4.328085122666891f /* 3*log2(e) */

__device__ __forceinline__ u16 f2bf(float f) {
    u32 u = __builtin_bit_cast(u32, f);
    u32 r = u + 0x7fffu + ((u >> 16) & 1u);
    return (u16)(r >> 16);
}
__device__ __forceinline__ float bf2f(u16 v) {
    return __builtin_bit_cast(float, (u32)v << 16);
}
// pack high-16s of two f32 (truncating bf16 cvt, 1 v_perm): low16=a, high16=b
__device__ __forceinline__ u32 pk_hi(float a, float b) {
    return __builtin_amdgcn_perm(__builtin_bit_cast(u32, b), __builtin_bit_cast(u32, a),
                                 0x07060302u);
}

// async global->LDS, 16B per lane; lds base wave-uniform (HW adds lane*16)
__device__ __forceinline__ void gload16(const u16* g, u16* lds) {
    __builtin_amdgcn_global_load_lds(
        (const __attribute__((address_space(1))) u32*)g,
        (__attribute__((address_space(3))) u32*)lds, 16, 0, 0);
}

// 128B-row XOR-swizzled fragment read: LDS chunk ch holds global chunk
// ch^(row&7); reading global chunk kidx -> LDS chunk kidx^(row&7).
__device__ __forceinline__ bf16x8 frag64(const u16* base, int row, int kidx) {
    return *(const bf16x8*)(base + row * 64 + ((kidx ^ (row & 7)) * 8));
}

// ---------------------------------------------------------------------------
// GEMM core: acc[4][4] += A[M,K] @ B[N,K]^T 128x128 tile, BK=64 (v15: half
// the barrier drains of BK=32; measured -3us vs BK=32). 32 MFMA per barrier
// pair. LDS 2x16KB, 128B rows with (row&7) XOR chunk swizzle. Default block
// mapping (v16's XCD remap regressed +6us).
// ---------------------------------------------------------------------------
__device__ __forceinline__ void gemm_core(f32x4 acc[4][4],
                                          const u16* __restrict__ A, const u16* __restrict__ B,
                                          int Kiter, int lda, int ldb,
                                          long m0, long n0, u16* As, u16* Bs) {
    const int tid = threadIdx.x;
    const int lane = tid & 63;
    const int wave = tid >> 6;
    const int r15 = lane & 15;
    const int qd = lane >> 4;
    const int wm = (wave >> 1) * 64;
    const int wn = (wave & 1) * 64;

    // staging: 16 segs of 8 rows (128B each); wave w stages segs 4w..4w+3
    const int lr0 = lane >> 3;
    const int lc0 = lane & 7;
    const u16* Aps[4];
    const u16* Bps[4];
#pragma unroll
    for (int i = 0; i < 4; i++) {
        int s = wave * 4 + i;
        int row = s * 8 + lr0;
        int c = lc0 ^ (row & 7);
        Aps[i] = A + (m0 + row) * lda + c * 8;
        Bps[i] = B + (n0 + row) * ldb + c * 8;
    }

    for (int kt = 0; kt < Kiter; kt += 64) {
        __syncthreads();
#pragma unroll
        for (int i = 0; i < 4; i++) {
            gload16(Aps[i] + kt, As + (wave * 4 + i) * 512);
            gload16(Bps[i] + kt, Bs + (wave * 4 + i) * 512);
        }
        __syncthreads();
#pragma unroll
        for (int kk = 0; kk < 2; kk++) {
            bf16x8 af[4], bfr[4];
#pragma unroll
            for (int i = 0; i < 4; i++)
                af[i] = frag64(As, wm + i * 16 + r15, kk * 4 + qd);
#pragma unroll
            for (int j = 0; j < 4; j++)
                bfr[j] = frag64(Bs, wn + j * 16 + r15, kk * 4 + qd);
#pragma unroll
            for (int i = 0; i < 4; i++)
#pragma unroll
                for (int j = 0; j < 4; j++)
                    acc[i][j] = __builtin_amdgcn_mfma_f32_16x16x32_bf16(af[i], bfr[j], acc[i][j], 0, 0, 0);
        }
    }
}

// ---------------------------------------------------------------------------
// Fused q/k/v projections. launch_bounds (256,3): v18's (256,4) SPILLED --
// acc (64 AGPR) + 64 arch VGPR = exactly the 128-reg cap at 4 waves/SIMD, so
// the LN-epilogue live set + 8 staging pointers went to scratch (WRITE_SIZE
// 12->103MB, gemm_qkv 64us). 3 blocks/CU is the register-demand optimum.
// z<=1: per-head LN epilogue (z==0 folds -log2(e)*SIG_SCALE into the
// affine). z==2: V written transposed into vt[(b*16+h)*64+d][2048].
// ---------------------------------------------------------------------------
__global__ __launch_bounds__(256, 3) void gemm_qkv(const u16* __restrict__ xq, const u16* __restrict__ keyb,
                                                   const u16* __restrict__ Wqb, const u16* __restrict__ Wkb,
                                                   const u16* __restrict__ Wvb,
                                                   const float* __restrict__ qns, const float* __restrict__ qnb,
                                                   const float* __restrict__ kns, const float* __restrict__ knb,
                                                   u16* __restrict__ qln, u16* __restrict__ kln,
                                                   u16* __restrict__ vt) {
    __shared__ __attribute__((aligned(16))) u16 As[128 * 64];
    __shared__ __attribute__((aligned(16))) u16 Bs[128 * 64];
    const int z = blockIdx.z;
    const u16* A = (z == 0) ? xq : keyb;
    const u16* B = (z == 0) ? Wqb : ((z == 1) ? Wkb : Wvb);
    const long m0 = (long)blockIdx.x * 128;
    const long n0 = (long)blockIdx.y * 128;

    f32x4 acc[4][4];
#pragma unroll
    for (int i = 0; i < 4; i++)
#pragma unroll
        for (int j = 0; j < 4; j++) acc[i][j] = (f32x4){0.f, 0.f, 0.f, 0.f};

    gemm_core(acc, A, B, 1024, 1024, 1024, m0, n0, As, Bs);

    const int lane = threadIdx.x & 63;
    const int wave = threadIdx.x >> 6;
    const int r15 = lane & 15;
    const int qd = lane >> 4;
    const int wm = (wave >> 1) * 64;
    const int wn = (wave & 1) * 64;

    if (z <= 1) {
        u16* C = (z == 0) ? qln : kln;
        const float* sc_ = (z == 0) ? qns : kns;
        const float* bs_ = (z == 0) ? qnb : knb;
        const float post = (z == 0) ? SIG_SCALE_F * NLOG2E : SIG_SCALE_F;
        float scl[4], bia[4];
#pragma unroll
        for (int j = 0; j < 4; j++) {
            scl[j] = sc_[j * 16 + r15] * post;
            bia[j] = bs_[j * 16 + r15] * post;
        }
#pragma unroll
        for (int i = 0; i < 4; i++) {
#pragma unroll
            for (int rr = 0; rr < 4; rr++) {
                float a0 = acc[i][0][rr], a1 = acc[i][1][rr], a2 = acc[i][2][rr], a3 = acc[i][3][rr];
                float s1 = (a0 + a1) + (a2 + a3);
                float s2 = __builtin_fmaf(a3, a3,
                           __builtin_fmaf(a2, a2, __builtin_fmaf(a1, a1, a0 * a0)));
#pragma unroll
                for (int off = 1; off <= 8; off <<= 1) {
                    s1 += __shfl_xor(s1, off, 64);
                    s2 += __shfl_xor(s2, off, 64);
                }
                float mu = s1 * (1.0f / 64.0f);
                float var = __builtin_fmaf(-mu, mu, s2 * (1.0f / 64.0f));
                float rs = rsqrtf(var + LN_EPS);
                long row = m0 + wm + i * 16 + qd * 4 + rr;
#pragma unroll
                for (int j = 0; j < 4; j++) {
                    long col = n0 + wn + j * 16 + r15;
                    float o = __builtin_fmaf((acc[i][j][rr] - mu) * rs, scl[j], bia[j]);
                    C[row * 1024 + col] = f2bf(o);
                }
            }
        }
    } else {
        // direct transposed V write: row -> (b, kk), col -> (h, d)
#pragma unroll
        for (int i = 0; i < 4; i++)
#pragma unroll
            for (int rr = 0; rr < 4; rr++) {
                int grow = (int)(m0 + wm + i * 16 + qd * 4 + rr);
                int bb = grow >> 11;
                int kk = grow & 2047;
#pragma unroll
                for (int j = 0; j < 4; j++) {
                    int col = (int)(n0 + wn + j * 16 + r15);
                    int hh = col >> 6;
                    int dd = col & 63;
                    vt[((size_t)(bb * 16 + hh) * 64 + dd) * 2048 + kk] = f2bf(acc[i][j][rr]);
                }
            }
    }
}

// output projection, split-K=2: grid (32, 8, 2), K=512/block (8 BK-64 iters),
// bf16 partials. (256,4) is safe here: trivial epilogue, no spill (verified
// by clean WRITE_SIZE across all rounds).
__global__ __launch_bounds__(256, 4) void gemm_o(const u16* __restrict__ ctx, const u16* __restrict__ Wob,
                                                 u16* __restrict__ opre) {
    __shared__ __attribute__((aligned(16))) u16 As[128 * 64];
    __shared__ __attribute__((aligned(16))) u16 Bs[128 * 64];
    const int z = blockIdx.z;
    const int koff = z * 512;
    u16* C = opre + (size_t)z * 4194304;
    const long m0 = (long)blockIdx.x * 128;
    const long n0 = (long)blockIdx.y * 128;
    f32x4 acc[4][4];
#pragma unroll
    for (int i = 0; i < 4; i++)
#pragma unroll
        for (int j = 0; j < 4; j++) acc[i][j] = (f32x4){0.f, 0.f, 0.f, 0.f};
    gemm_core(acc, ctx + koff, Wob + koff, 512, 1024, 1024, m0, n0, As, Bs);

    const int lane = threadIdx.x & 63;
    const int wave = threadIdx.x >> 6;
    const int r15 = lane & 15;
    const int qd = lane >> 4;
    const int wm = (wave >> 1) * 64;
    const int wn = (wave & 1) * 64;
#pragma unroll
    for (int i = 0; i < 4; i++)
#pragma unroll
        for (int rr = 0; rr < 4; rr++) {
            long row = m0 + wm + i * 16 + qd * 4 + rr;
#pragma unroll
            for (int j = 0; j < 4; j++)
                C[row * 1024 + n0 + wn + j * 16 + r15] = f2bf(acc[i][j][rr]);
        }
}

// ---------------------------------------------------------------------------
// Fused sigmoid attention v14 (UNCHANGED -- best measured: 51.5us). Pipelined
// stage(i+1) || S(i) || PV(i-1) || sig(i), single pg buffer carrying P
// across one barrier, per-mt-tile S (no spill at the 128-reg cap), 3-slot V
// rotation via SGPR scalars, V slot 2 overlays Qs, LDS 80KB = 2 blocks/CU,
// v_rcp (trans ~2cy issue), accS C-init = BIAS_L2E with q pre-scaled by
// NLOG2E. Register-capped at 4 waves/SIMD; residual ~46% latency stall is
// structural at this occupancy.
// ---------------------------------------------------------------------------
__global__ __launch_bounds__(512, 4) void attn_sigmoid_v14(const u16* __restrict__ q,
                                                           const u16* __restrict__ k,
                                                           const u16* __restrict__ vt,
                                                           u16* __restrict__ ctx) {
    // [Qs | V slot2] 16K, Ks[2][2] 32K, Vs[slot0..1][2] 32K  = 80 KB
    __shared__ __attribute__((aligned(16))) u16 Sh[8192 + 16384 + 16384];
    u16* Qs = Sh;
    u16* Ks = Sh + 8192;
    u16* Vs = Sh + 8192 + 16384;
    float* Obuf = (float*)(Sh + 8192);  // 32 KB, overlays Ks (dead at epilogue)

    const int tid = threadIdx.x;
    const int lane = tid & 63;
    const int wave = tid >> 6;       // 0..7
    const int l31 = lane & 31;
    const int h = lane >> 5;
    const int qsub = wave & 3;       // 32-q-row group
    const int kh = wave >> 2;        // k half
    const int hd = blockIdx.x;       // head (XCD-aligned)
    const int q0 = blockIdx.y * 128;
    const int b = blockIdx.z;
    const int bh = b * 16 + hd;

    const int lr0 = lane >> 3;
    const int lc0 = lane & 7;
    const int wsub = wave & 3;
    const int kbeg = kh * 1024;

    auto kptr = [&](int slot) { return Ks + (slot * 2 + kh) * 4096; };
    auto vptr = [&](int slot) { return (slot == 2 ? Sh : Vs + slot * 8192) + kh * 4096; };

    // stage this kh-half's 64x64 K,V chunk (8+8 segs over the half's 4 waves)
    auto stageKV = [&](int kslot, int vslot, int kc) {
        u16* kd = kptr(kslot);
        u16* vd = vptr(vslot);
#pragma unroll
        for (int i = 0; i < 2; i++) {
            int s = wsub * 2 + i;
            int row = s * 8 + lr0;
            int c = lc0 ^ (row & 7);
            gload16(k + (size_t)(b * 2048 + kc + row) * 1024 + hd * 64 + c * 8, kd + s * 512);
            gload16(vt + (size_t)(bh * 64 + row) * 2048 + kc + c * 8, vd + s * 512);
        }
    };

    {   // stage Q tile 128x64 (16 segs, wave stages segs {2w, 2w+1}) + chunk 0
#pragma unroll
        for (int i = 0; i < 2; i++) {
            int s = wave * 2 + i;
            int row = s * 8 + lr0;
            int c = lc0 ^ (row & 7);
            gload16(q + (size_t)(b * 2048 + q0 + row) * 1024 + hd * 64 + c * 8, Qs + s * 512);
        }
        stageKV(0, 0, kbeg);
    }
    __syncthreads();
    // hoist Q B-frags: wave's 32 q-rows = qsub*32 + l31  (Qs dead after this)
    bf16x8 qB[4];
#pragma unroll
    for (int dblk = 0; dblk < 4; dblk++)
        qB[dblk] = frag64(Qs, qsub * 32 + l31, dblk * 2 + h);

    f32x16 accO[2];
#pragma unroll
    for (int dt = 0; dt < 2; dt++)
#pragma unroll
        for (int r = 0; r < 16; r++) accO[dt][r] = 0.f;

    u32 pg[2][4][2];

    // S^T for one 32k x 32q tile: C-init = BIAS_L2E (bias via MFMA C-input)
    auto do_S_mt = [&](int kslot, int mt) -> f32x16 {
        const u16* Ksh = kptr(kslot);
        f32x16 s;
#pragma unroll
        for (int r = 0; r < 16; r++) s[r] = BIAS_L2E;
        __builtin_amdgcn_s_setprio(1);
#pragma unroll
        for (int dblk = 0; dblk < 4; dblk++) {
            bf16x8 aK = frag64(Ksh, mt * 32 + l31, dblk * 2 + h);
            s = __builtin_amdgcn_mfma_f32_32x32x16_bf16(aK, qB[dblk], s, 0, 0, 0);
        }
        __builtin_amdgcn_s_setprio(0);
        return s;
    };
    // sigmoid + pack one mt-tile: p = rcp(1 + exp2(s))  (s = NLOG2E*S + BIAS)
    auto do_sig_mt = [&](const f32x16& s, int mt) {
#pragma unroll
        for (int g = 0; g < 4; g++) {
            float p[4];
#pragma unroll
            for (int e = 0; e < 4; e++) {
                float u = __builtin_amdgcn_exp2f(s[g * 4 + e]);
                p[e] = __builtin_amdgcn_rcpf(1.0f + u);
            }
            pg[mt][g][0] = pk_hi(p[0], p[1]);
            pg[mt][g][1] = pk_hi(p[2], p[3]);
        }
    };
    // PV for the previous chunk whose packed P lives in pg
    auto do_PV = [&](int vslot) {
        const u16* Vsh = vptr(vslot);
        __builtin_amdgcn_s_setprio(1);
#pragma unroll
        for (int mt = 0; mt < 2; mt++)
#pragma unroll
            for (int kblk = 0; kblk < 2; kblk++) {
                int glo = kblk * 2, ghi = kblk * 2 + 1;
                u32x2 r0 = __builtin_amdgcn_permlane32_swap(pg[mt][glo][0], pg[mt][ghi][0], false, false);
                u32x2 r1 = __builtin_amdgcn_permlane32_swap(pg[mt][glo][1], pg[mt][ghi][1], false, false);
                u32x4 fr;
                fr[0] = r0[0];
                fr[1] = r1[0];
                fr[2] = r0[1];
                fr[3] = r1[1];
                bf16x8 aP = __builtin_bit_cast(bf16x8, fr);
#pragma unroll
                for (int dt = 0; dt < 2; dt++) {
                    bf16x8 bV = frag64(Vsh, dt * 32 + l31, mt * 4 + kblk * 2 + h);
                    accO[dt] = __builtin_amdgcn_mfma_f32_32x32x16_bf16(aP, bV, accO[dt], 0, 0, 0);
                }
            }
        __builtin_amdgcn_s_setprio(0);
    };

    // V-slot rotation (uniform scalars -> SGPR): chunk i lives in slot i%3
    int vs_prev = 2, vs_cur = 0, vs_next = 1;
#pragma unroll 1
    for (int it = 0; it < 16; ++it) {
        if (it < 15) stageKV((it + 1) & 1, vs_next, kbeg + (it + 1) * 64);
        f32x16 s0 = do_S_mt(it & 1, 0);
        if (it > 0) do_PV(vs_prev);  // reads pg of chunk it-1 (covers s0 latency)
        do_sig_mt(s0, 0);
        f32x16 s1 = do_S_mt(it & 1, 1);
        do_sig_mt(s1, 1);
        __syncthreads();
        int t = vs_prev; vs_prev = vs_cur; vs_cur = vs_next; vs_next = t;
    }
    do_PV(vs_prev);  // drain: PV of chunk 15 (slot 15%3 = 0)

    // merge k-halves through LDS; kh=0 waves write final ctx
    if (kh == 1) {
#pragma unroll
        for (int dt = 0; dt < 2; dt++)
#pragma unroll
            for (int r = 0; r < 16; r++) {
                int ql = qsub * 32 + (r & 3) + 8 * (r >> 2) + 4 * h;
                Obuf[ql * 64 + dt * 32 + l31] = accO[dt][r];
            }
    }
    __syncthreads();
    if (kh == 0) {
#pragma unroll
        for (int dt = 0; dt < 2; dt++)
#pragma unroll
            for (int r = 0; r < 16; r++) {
                int ql = qsub * 32 + (r & 3) + 8 * (r >> 2) + 4 * h;
                float s = accO[dt][r] + Obuf[ql * 64 + dt * 32 + l31];
                ctx[(size_t)(b * 2048 + q0 + ql) * 1024 + hd * 64 + dt * 32 + l31] = f2bf(s);
            }
    }
}

// ---------------------------------------------------------------------------
// prep: fp32->bf16 of 4 weights (blocks 0..4095) + key_feats (4096..6143),
// then row-LN of query (blocks 6144..10239). One launch.
// ---------------------------------------------------------------------------
__global__ __launch_bounds__(256) void prep(const float* __restrict__ w0, const float* __restrict__ w1,
                                            const float* __restrict__ w2, const float* __restrict__ w3,
                                            const float* __restrict__ kf, const float* __restrict__ qf,
                                            const float* __restrict__ lnq_s, const float* __restrict__ lnq_b,
                                            u16* __restrict__ wdst, u16* __restrict__ kdst,
                                            u16* __restrict__ xq) {
    const int bx = blockIdx.x;
    const int tid = threadIdx.x;
    if (bx < 6144) {
        size_t e = ((size_t)bx * 256 + tid) * 4;
        const float* src;
        u16* dst;
        if (e < 4194304) {
            src = ((e >> 20) == 0 ? w0 : (e >> 20) == 1 ? w1 : (e >> 20) == 2 ? w2 : w3) + (e & 1048575);
            dst = wdst + e;
        } else {
            size_t off = e - 4194304;
            src = kf + off;
            dst = kdst + off;
        }
        float4 xv = *(const float4*)src;
        u16x4 o;
        o[0] = f2bf(xv.x);
        o[1] = f2bf(xv.y);
        o[2] = f2bf(xv.z);
        o[3] = f2bf(xv.w);
        *(u16x4*)dst = o;
    } else {
        __shared__ float s1buf[4], s2buf[4];
        const int row = bx - 6144;
        const size_t base = (size_t)row * 1024 + tid * 4;
        const float4 xv = *(const float4*)(qf + base);
        float s1 = xv.x + xv.y + xv.z + xv.w;
        float s2 = xv.x * xv.x + xv.y * xv.y + xv.z * xv.z + xv.w * xv.w;
        int lane = tid & 63, wave = tid >> 6;
#pragma unroll
        for (int off = 32; off > 0; off >>= 1) {
            s1 += __shfl_down(s1, off, 64);
            s2 += __shfl_down(s2, off, 64);
        }
        if (lane == 0) { s1buf[wave] = s1; s2buf[wave] = s2; }
        __syncthreads();
        s1 = s1buf[0] + s1buf[1] + s1buf[2] + s1buf[3];
        s2 = s2buf[0] + s2buf[1] + s2buf[2] + s2buf[3];
        float mu = s1 * (1.0f / 1024.0f);
        float var = s2 * (1.0f / 1024.0f) - mu * mu;
        float rs = rsqrtf(var + LN_EPS);
        const float4 scv = *(const float4*)(lnq_s + tid * 4);
        const float4 bsv = *(const float4*)(lnq_b + tid * 4);
        u16x4 o;
        o[0] = f2bf((xv.x - mu) * rs * scv.x + bsv.x);
        o[1] = f2bf((xv.y - mu) * rs * scv.y + bsv.y);
        o[2] = f2bf((xv.z - mu) * rs * scv.z + bsv.z);
        o[3] = f2bf((xv.w - mu) * rs * scv.w + bsv.w);
        *(u16x4*)(xq + base) = o;
    }
}

// ---------------------------------------------------------------------------
// Final: out = LN(resid + gamma*(o0+o1)) (fp32, bf16 partials, split-K=2)
// ---------------------------------------------------------------------------
__global__ __launch_bounds__(256) void final_ln(const float* __restrict__ resid,
                                                const u16* __restrict__ opre,
                                                const float* __restrict__ gamma,
                                                const float* __restrict__ sc,
                                                const float* __restrict__ bs,
                                                float* __restrict__ out) {
    __shared__ float s1buf[4], s2buf[4];
    const int row = blockIdx.x;
    const int tid = threadIdx.x;
    const size_t base = (size_t)row * 1024 + tid * 4;
    float4 rv = *(const float4*)(resid + base);
    u16x4 p0 = *(const u16x4*)(opre + base);
    u16x4 p1 = *(const u16x4*)(opre + 4194304 + base);
    float4 gv = *(const float4*)(gamma + tid * 4);
    float4 xv;
    xv.x = rv.x + gv.x * (bf2f(p0[0]) + bf2f(p1[0]));
    xv.y = rv.y + gv.y * (bf2f(p0[1]) + bf2f(p1[1]));
    xv.z = rv.z + gv.z * (bf2f(p0[2]) + bf2f(p1[2]));
    xv.w = rv.w + gv.w * (bf2f(p0[3]) + bf2f(p1[3]));
    float s1 = xv.x + xv.y + xv.z + xv.w;
    float s2 = xv.x * xv.x + xv.y * xv.y + xv.z * xv.z + xv.w * xv.w;
    int lane = tid & 63, wave = tid >> 6;
#pragma unroll
    for (int off = 32; off > 0; off >>= 1) {
        s1 += __shfl_down(s1, off, 64);
        s2 += __shfl_down(s2, off, 64);
    }
    if (lane == 0) { s1buf[wave] = s1; s2buf[wave] = s2; }
    __syncthreads();
    s1 = s1buf[0] + s1buf[1] + s1buf[2] + s1buf[3];
    s2 = s2buf[0] + s2buf[1] + s2buf[2] + s2buf[3];
    float mu = s1 * (1.0f / 1024.0f);
    float var = s2 * (1.0f / 1024.0f) - mu * mu;
    float rs = rsqrtf(var + LN_EPS);
    const float4 scv = *(const float4*)(sc + tid * 4);
    const float4 bsv = *(const float4*)(bs + tid * 4);
    float4 o;
    o.x = (xv.x - mu) * rs * scv.x + bsv.x;
    o.y = (xv.y - mu) * rs * scv.y + bsv.y;
    o.z = (xv.z - mu) * rs * scv.z + bsv.z;
    o.w = (xv.w - mu) * rs * scv.w + bsv.w;
    *(float4*)(out + base) = o;
}

extern "C" void kernel_launch(void* const* d_in, const int* in_sizes, int n_in,
                              void* d_out, int out_size, void* d_ws, size_t ws_size,
                              hipStream_t stream) {
    const float* qf    = (const float*)d_in[0];
    const float* kf    = (const float*)d_in[1];
    const float* Wq    = (const float*)d_in[2];
    const float* Wk    = (const float*)d_in[3];
    const float* Wv    = (const float*)d_in[4];
    const float* Wo    = (const float*)d_in[5];
    const float* qn_s  = (const float*)d_in[6];
    const float* qn_b  = (const float*)d_in[7];
    const float* kn_s  = (const float*)d_in[8];
    const float* kn_b  = (const float*)d_in[9];
    const float* lnq_s = (const float*)d_in[10];
    const float* lnq_b = (const float*)d_in[11];
    const float* lno_s = (const float*)d_in[12];
    const float* lno_b = (const float*)d_in[13];
    const float* gamma = (const float*)d_in[14];
    float* out = (float*)d_out;

    char* ws = (char*)d_ws;
    const size_t MB = 1024 * 1024;
    u16* Wqb   = (u16*)(ws + 0 * MB);   // 4 weights contiguous, 8 MB
    u16* Wkb   = (u16*)(ws + 2 * MB);
    u16* Wvb   = (u16*)(ws + 4 * MB);
    u16* Wob   = (u16*)(ws + 6 * MB);
    u16* xq    = (u16*)(ws + 8 * MB);    // dead after gemm_qkv
    u16* ctx   = (u16*)(ws + 8 * MB);    // reuse xq (attn writes merged ctx)
    u16* keyb  = (u16*)(ws + 16 * MB);   // dead after gemm_qkv
    u16* qln   = (u16*)(ws + 24 * MB);   // dead after attn
    u16* kln   = (u16*)(ws + 32 * MB);   // dead after attn
    u16* vt    = (u16*)(ws + 48 * MB);   // written by gemm_qkv z=2, dead after attn
    u16* opre  = (u16*)(ws + 24 * MB);   // 2 x 8 MB partials (reuse 24..40)

    prep<<<dim3(10240), 256, 0, stream>>>(Wq, Wk, Wv, Wo, kf, qf, lnq_s, lnq_b, Wqb, keyb, xq);

    gemm_qkv<<<dim3(32, 8, 3), 256, 0, stream>>>(xq, keyb, Wqb, Wkb, Wvb,
                                                 qn_s, qn_b, kn_s, kn_b, qln, kln, vt);

    attn_sigmoid_v14<<<dim3(16, 16, 2), 512, 0, stream>>>(qln, kln, vt, ctx);

    gemm_o<<<dim3(32, 8, 2), 256, 0, stream>>>(ctx, Wob, opre);
    final_ln<<<dim3(4096), 256, 0, stream>>>(qf, opre, gamma, lno_s, lno_b, out);
}